// Round 7
// baseline (418.511 us; speedup 1.0000x reference)
//
#include <hip/hip_runtime.h>
#include <hip/hip_bf16.h>

// Problem constants
#define DM   1024
#define NH   16
#define DK   64
#define RK   16
#define BB   2
#define LL   2048
#define TT   (BB*LL)
#define HR32 512            // NH * padded-rank(32)

// Interface (established r0-r5): inputs fp32, output fp32.
// r7: pre-cast operands to bf16 once; all GEMMs pure-bf16 MFMA staging;
// attention barrier-free with direct-global K/V fragments (LDS only for the
// wave-private E transpose).

typedef float f4  __attribute__((ext_vector_type(4)));
typedef short s8v __attribute__((ext_vector_type(8)));

static __device__ __forceinline__ unsigned short f2b(float f) {
  __hip_bfloat16 h = __float2bfloat16(f);
  unsigned short u;
  __builtin_memcpy(&u, &h, 2);
  return u;
}

// ---------------------------------------------------------------------------
// cast fp32 -> bf16, vectorized grid-stride (n4 = element count / 4)
// ---------------------------------------------------------------------------
__global__ __launch_bounds__(256) void cast_bf16(
    const float* __restrict__ src, unsigned short* __restrict__ dst, int n4) {
  int i = blockIdx.x * 256 + threadIdx.x;
  const int stride = gridDim.x * 256;
  for (; i < n4; i += stride) {
    const float4 v = ((const float4*)src)[i];
    ushort4 o;
    o.x = f2b(v.x); o.y = f2b(v.y); o.z = f2b(v.z); o.w = f2b(v.w);
    ((ushort4*)dst)[i] = o;
  }
}

// ---------------------------------------------------------------------------
// fused low-rank weights (tiled, coalesced):
//   At[h*32+r][i] = sum_d W[h*64+d][i] * U[h][d][r]  (bf16), rows r=16..31 = 0
// grid (DM/64, NH), 256 threads: il = tid&63 (i), rr = tid>>6 (4 r's each)
// ---------------------------------------------------------------------------
__global__ __launch_bounds__(256) void fuse_weights2(
    const float* __restrict__ W, const float* __restrict__ U,
    unsigned short* __restrict__ At) {
  __shared__ float Us[64][16];
  __shared__ float Ws[4][64];
  const int i0 = blockIdx.x * 64;
  const int h  = blockIdx.y;
  const int tid = threadIdx.x;
  const int il = tid & 63, rr = tid >> 6;
  for (int t = tid; t < 64*16; t += 256)
    Us[t >> 4][t & 15] = U[(size_t)(h*DK + (t >> 4))*RK + (t & 15)];
  float acc[4] = {};
  for (int d0 = 0; d0 < DK; d0 += 4) {
    __syncthreads();               // also covers the Us staging on first pass
    Ws[rr][il] = W[(size_t)(h*DK + d0 + rr)*DM + i0 + il];
    __syncthreads();
#pragma unroll
    for (int dd = 0; dd < 4; ++dd) {
      const float w = Ws[dd][il];
#pragma unroll
      for (int j = 0; j < 4; ++j)
        acc[j] += w * Us[d0 + dd][rr*4 + j];
    }
  }
#pragma unroll
  for (int j = 0; j < 4; ++j) {
    At[(size_t)(h*32 + rr*4 + j)*DM + i0 + il]      = f2b(acc[j]);
    At[(size_t)(h*32 + 16 + rr*4 + j)*DM + i0 + il] = 0;  // rank padding
  }
}

__global__ void bias_proj(const float* __restrict__ b,
                          const float* __restrict__ U,
                          float* __restrict__ bp) {
  int hr = threadIdx.x;
  int h = hr >> 4, r = hr & 15;
  float acc = 0.f;
  for (int d = 0; d < DK; ++d)
    acc += b[h*DK + d] * U[(size_t)(h*DK + d)*RK + r];
  bp[h*32 + r] = acc;
  bp[h*32 + 16 + r] = 0.f;
}

// ---------------------------------------------------------------------------
// Pure-bf16 MFMA GEMM: C[t][n] = sum_k A[t][k]*B[n][k] + bias[n]
// M=4096, K=1024. 128x128 tile, BK=32, 4 waves. LDS rows stride 40 halfs.
// MODE: 0 = fp32 row-major; 1 = bf16 row-major; 2 = bf16 transposed Vt[b][n][l]
// ---------------------------------------------------------------------------
template<int N_, int MODE>
__global__ __launch_bounds__(256) void gemm_bf16(
    const unsigned short* __restrict__ Ag, const unsigned short* __restrict__ Bg,
    const float* __restrict__ bias, void* __restrict__ Cgv) {
  __shared__ unsigned short Xs[128*40];
  __shared__ unsigned short Bs[128*40];
  const int t0 = blockIdx.x * 128, n0 = blockIdx.y * 128;
  const int tid  = threadIdx.x;
  const int wave = tid >> 6, lane = tid & 63;
  const int quad = lane >> 4, l15 = lane & 15;
  const int mh = (wave & 1) * 64, nh = (wave >> 1) * 64;
  const int srow = tid >> 1, spart = tid & 1;

  const f4 z = {0.f, 0.f, 0.f, 0.f};
  f4 acc[4][4];
#pragma unroll
  for (int a = 0; a < 4; ++a)
#pragma unroll
    for (int b = 0; b < 4; ++b) acc[a][b] = z;

  for (int k0 = 0; k0 < DM; k0 += 32) {
    __syncthreads();
    {
      const s8v* srcA = (const s8v*)&Ag[(size_t)(t0 + srow)*DM + k0 + spart*16];
      *(s8v*)&Xs[srow*40 + spart*16]     = srcA[0];
      *(s8v*)&Xs[srow*40 + spart*16 + 8] = srcA[1];
      const s8v* srcB = (const s8v*)&Bg[(size_t)(n0 + srow)*DM + k0 + spart*16];
      *(s8v*)&Bs[srow*40 + spart*16]     = srcB[0];
      *(s8v*)&Bs[srow*40 + spart*16 + 8] = srcB[1];
    }
    __syncthreads();

    s8v af[4], bf[4];
#pragma unroll
    for (int ms = 0; ms < 4; ++ms)
      af[ms] = *(const s8v*)&Xs[(mh + ms*16 + l15)*40 + quad*8];
#pragma unroll
    for (int ns = 0; ns < 4; ++ns)
      bf[ns] = *(const s8v*)&Bs[(nh + ns*16 + l15)*40 + quad*8];
#pragma unroll
    for (int ms = 0; ms < 4; ++ms)
#pragma unroll
      for (int ns = 0; ns < 4; ++ns)
        acc[ms][ns] = __builtin_amdgcn_mfma_f32_16x16x32_bf16(
            af[ms], bf[ns], acc[ms][ns], 0, 0, 0);
  }

#pragma unroll
  for (int ms = 0; ms < 4; ++ms) {
    const int tb = t0 + mh + ms*16 + quad*4;
#pragma unroll
    for (int ns = 0; ns < 4; ++ns) {
      const int o = n0 + nh + ns*16 + l15;
      const float bv = bias[o];
      f4 a = acc[ms][ns];
      if (MODE == 0) {
        float* C = (float*)Cgv;
#pragma unroll
        for (int rg = 0; rg < 4; ++rg)
          C[(size_t)(tb + rg)*N_ + o] = a[rg] + bv;
      } else if (MODE == 1) {
        unsigned short* C = (unsigned short*)Cgv;
#pragma unroll
        for (int rg = 0; rg < 4; ++rg)
          C[(size_t)(tb + rg)*N_ + o] = f2b(a[rg] + bv);
      } else {
        unsigned short* C = (unsigned short*)Cgv;   // Vt[b][o][l]
        const int bb = tb >> 11, l = tb & 2047;
        ushort4 pk;
        pk.x = f2b(a[0] + bv); pk.y = f2b(a[1] + bv);
        pk.z = f2b(a[2] + bv); pk.w = f2b(a[3] + bv);
        *(ushort4*)&C[((size_t)bb*DM + o)*LL + l] = pk;
      }
    }
  }
}

// ---------------------------------------------------------------------------
// Attention v2: barrier-free. grid (LL/64, NH, BB), 256 threads = 4 waves.
// Wave owns 16 q rows. K/V fragments loaded directly from global (L1/L2-hot);
// only LDS use is the wave-private E transpose (stride 68 = bank-uniform,
// 16B-aligned). No __syncthreads anywhere.
// ---------------------------------------------------------------------------
__global__ __launch_bounds__(256) void attention_mfma2(
    const unsigned short* __restrict__ Qp, const unsigned short* __restrict__ Kp,
    const unsigned short* __restrict__ Vt, const unsigned char* __restrict__ msk,
    unsigned short* __restrict__ ctx) {
  __shared__ float Es[4][16*68];
  const int q0 = blockIdx.x * 64, h = blockIdx.y, b = blockIdx.z;
  const int tid = threadIdx.x, wave = tid >> 6, lane = tid & 63;
  const int quad = lane >> 4, l15 = lane & 15;
  float* __restrict__ Ew = Es[wave];

  // persistent Q A-frag: m = l15 within the wave's 16 q rows, k = quad*8+j
  const s8v qfrag = *(const s8v*)&Qp[
      (size_t)(b*LL + q0 + wave*16 + l15)*HR32 + h*32 + quad*8];

  const unsigned short* __restrict__ Kbase =
      Kp + (size_t)(b*LL)*HR32 + h*32 + quad*8;
  const unsigned short* __restrict__ Vbase =
      Vt + ((size_t)b*DM + h*DK)*LL + quad*8;
  const unsigned char* __restrict__ Mbase = msk + (size_t)b*LL;

  const f4 z = {0.f, 0.f, 0.f, 0.f};
  f4 acc[4];
#pragma unroll
  for (int d = 0; d < 4; ++d) acc[d] = z;
  float den[4] = {0.f, 0.f, 0.f, 0.f};

  for (int k0 = 0; k0 < LL; k0 += 64) {
    // ---- S phase: 4 k-subtiles of 16; exp -> wave-private LDS ----
#pragma unroll
    for (int nt = 0; nt < 4; ++nt) {
      const s8v kf = *(const s8v*)&Kbase[(size_t)(k0 + nt*16 + l15)*HR32];
      f4 s = __builtin_amdgcn_mfma_f32_16x16x32_bf16(qfrag, kf, z, 0, 0, 0);
      const float m = Mbase[k0 + nt*16 + l15] ? 0.f : 1.f;
#pragma unroll
      for (int rg = 0; rg < 4; ++rg) {
        const float e = __expf(s[rg] * 0.25f) * m;
        den[rg] += e;
        Ew[(quad*4 + rg)*68 + nt*16 + l15] = e;
      }
    }
    // ---- PV phase: 2 K-steps of 32, V fragments direct from global ----
#pragma unroll
    for (int ks = 0; ks < 2; ++ks) {
      const float4 e0 = *(const float4*)&Ew[l15*68 + ks*32 + quad*8];
      const float4 e1 = *(const float4*)&Ew[l15*68 + ks*32 + quad*8 + 4];
      s8v ef;
      ef[0] = (short)f2b(e0.x); ef[1] = (short)f2b(e0.y);
      ef[2] = (short)f2b(e0.z); ef[3] = (short)f2b(e0.w);
      ef[4] = (short)f2b(e1.x); ef[5] = (short)f2b(e1.y);
      ef[6] = (short)f2b(e1.z); ef[7] = (short)f2b(e1.w);
#pragma unroll
      for (int dt = 0; dt < 4; ++dt) {
        const s8v vf = *(const s8v*)&Vbase[(size_t)(dt*16 + l15)*LL + k0 + ks*32];
        acc[dt] = __builtin_amdgcn_mfma_f32_16x16x32_bf16(ef, vf, acc[dt], 0, 0, 0);
      }
    }
  }

  // reduce softmax denominators across the 16 lanes of each quad group
#pragma unroll
  for (int rg = 0; rg < 4; ++rg) {
    float d = den[rg];
    d += __shfl_xor(d, 1); d += __shfl_xor(d, 2);
    d += __shfl_xor(d, 4); d += __shfl_xor(d, 8);
    den[rg] = 1.f / fmaxf(d, 1e-30f);
  }

#pragma unroll
  for (int dt = 0; dt < 4; ++dt)
#pragma unroll
    for (int rg = 0; rg < 4; ++rg)
      ctx[(size_t)(b*LL + q0 + wave*16 + quad*4 + rg)*DM + h*DK + dt*16 + l15] =
          f2b(acc[dt][rg] * den[rg]);
}

// ---------------------------------------------------------------------------
extern "C" void kernel_launch(void* const* d_in, const int* in_sizes, int n_in,
                              void* d_out, int out_size, void* d_ws, size_t ws_size,
                              hipStream_t stream) {
  (void)in_sizes; (void)n_in; (void)out_size; (void)ws_size;
  const float* x_q   = (const float*)d_in[0];
  const float* x_kv  = (const float*)d_in[1];
  const float* Wq    = (const float*)d_in[2];
  const float* bq    = (const float*)d_in[3];
  const float* Wk    = (const float*)d_in[4];
  const float* bk    = (const float*)d_in[5];
  const float* Wv    = (const float*)d_in[6];
  const float* bv    = (const float*)d_in[7];
  const float* Wo    = (const float*)d_in[8];
  const float* bo    = (const float*)d_in[9];
  const float* U_bil = (const float*)d_in[10];
  const float* V_bil = (const float*)d_in[11];
  const unsigned char* pmask = (const unsigned char*)d_in[12];  // all-False
  float* out = (float*)d_out;

  // Workspace layout, 38.0 MB total (< r5's proven 44 MB).
  // ctx aliases xq_b: xq_b's last read (Qp GEMM) precedes attention in-stream.
  char* w = (char*)d_ws;
  unsigned short* xq_b  = (unsigned short*)(w);             //  8 MB
  unsigned short* xkv_b = (unsigned short*)(w +  8388608);  //  8 MB
  unsigned short* Wv_b  = (unsigned short*)(w + 16777216);  //  2 MB
  unsigned short* Wo_b  = (unsigned short*)(w + 18874368);  //  2 MB
  unsigned short* Atq   = (unsigned short*)(w + 20971520);  //  1 MB
  unsigned short* Atk   = (unsigned short*)(w + 22020096);  //  1 MB
  float*          bpq   = (float*)(w + 23068672);           //  2 KB
  float*          bpk   = (float*)(w + 23070720);           //  2 KB
  unsigned short* Qp    = (unsigned short*)(w + 23072768);  //  4 MB
  unsigned short* Kp    = (unsigned short*)(w + 27267072);  //  4 MB
  unsigned short* Vt    = (unsigned short*)(w + 31461376);  //  8 MB
  unsigned short* ctx   = xq_b;                             //  aliased

  cast_bf16<<<4096, 256, 0, stream>>>(x_q,  xq_b,  TT*DM/4);
  cast_bf16<<<4096, 256, 0, stream>>>(x_kv, xkv_b, TT*DM/4);
  cast_bf16<<<1024, 256, 0, stream>>>(Wv, Wv_b, DM*DM/4);
  cast_bf16<<<1024, 256, 0, stream>>>(Wo, Wo_b, DM*DM/4);
  fuse_weights2<<<dim3(DM/64, NH), 256, 0, stream>>>(Wq, U_bil, Atq);
  fuse_weights2<<<dim3(DM/64, NH), 256, 0, stream>>>(Wk, V_bil, Atk);
  bias_proj<<<1, 256, 0, stream>>>(bq, U_bil, bpq);
  bias_proj<<<1, 256, 0, stream>>>(bk, V_bil, bpk);
  gemm_bf16<512, 1><<<dim3(32, 4), 256, 0, stream>>>(xq_b,  Atq, bpq, Qp);
  gemm_bf16<512, 1><<<dim3(32, 4), 256, 0, stream>>>(xkv_b, Atk, bpk, Kp);
  gemm_bf16<1024, 2><<<dim3(32, 8), 256, 0, stream>>>(xkv_b, Wv_b, bv, Vt);
  attention_mfma2<<<dim3(LL/64, NH, BB), 256, 0, stream>>>(Qp, Kp, Vt, pmask, ctx);
  gemm_bf16<1024, 0><<<dim3(32, 8), 256, 0, stream>>>(ctx, Wo_b, bo, out);
}

// Round 9
// 277.976 us; speedup vs baseline: 1.5056x; 1.5056x over previous
//
#include <hip/hip_runtime.h>
#include <hip/hip_bf16.h>

// Problem constants
#define DM   1024
#define NH   16
#define DK   64
#define RK   16
#define BB   2
#define LL   2048
#define TT   (BB*LL)
#define HRK  256           // NH*RK (unpadded rank-16)

// Interface (established r0-r5): inputs fp32, output fp32.
// r9: r8 structure + numerics hardening:
//   - E' = e-1 stored bf16 (softmax weights ~1; bf16-round the DEVIATION only)
//   - ctx = (Vsum_fp32 + sum E'v)/den ; Vsum via tiny exact-fp32 kernel
//   - ctx fp32; out-GEMM stages A with fp32->bf16 cvt (r6-proven)

typedef float f4   __attribute__((ext_vector_type(4)));
typedef float f16v __attribute__((ext_vector_type(16)));
typedef short s8v  __attribute__((ext_vector_type(8)));

static __device__ __forceinline__ unsigned short f2b(float f) {
  __hip_bfloat16 h = __float2bfloat16(f);
  unsigned short u;
  __builtin_memcpy(&u, &h, 2);
  return u;
}
static __device__ __forceinline__ float b2f(unsigned short u) {
  __hip_bfloat16 h;
  __builtin_memcpy(&h, &u, 2);
  return __bfloat162float(h);
}

// ---------------------------------------------------------------------------
// cast all four fp32 operands to bf16 in one launch. grid (1024, 4).
// ---------------------------------------------------------------------------
__global__ __launch_bounds__(256) void cast_all(
    const float* __restrict__ s0, unsigned short* __restrict__ d0, int n0,
    const float* __restrict__ s1, unsigned short* __restrict__ d1, int n1,
    const float* __restrict__ s2, unsigned short* __restrict__ d2, int n2,
    const float* __restrict__ s3, unsigned short* __restrict__ d3, int n3) {
  const float* s; unsigned short* d; int n;
  switch (blockIdx.y) {
    case 0:  s = s0; d = d0; n = n0; break;
    case 1:  s = s1; d = d1; n = n1; break;
    case 2:  s = s2; d = d2; n = n2; break;
    default: s = s3; d = d3; n = n3; break;
  }
  for (int i = blockIdx.x*256 + threadIdx.x; i < n; i += gridDim.x*256) {
    const float4 v = ((const float4*)s)[i];
    ushort4 o;
    o.x = f2b(v.x); o.y = f2b(v.y); o.z = f2b(v.z); o.w = f2b(v.w);
    ((ushort4*)d)[i] = o;
  }
}

// ---------------------------------------------------------------------------
// fused low-rank weights (q & k in one launch via blockIdx.z):
//   At[h*16+r][i] = sum_d W[h*64+d][i] * U[h][d][r]   (bf16, unpadded)
// ---------------------------------------------------------------------------
__global__ __launch_bounds__(256) void fuse_w(
    const float* __restrict__ Wq, const float* __restrict__ Wk,
    const float* __restrict__ Uq, const float* __restrict__ Uk,
    unsigned short* __restrict__ Aq, unsigned short* __restrict__ Ak) {
  const float* W = blockIdx.z ? Wk : Wq;
  const float* U = blockIdx.z ? Uk : Uq;
  unsigned short* At = blockIdx.z ? Ak : Aq;
  __shared__ float Us[64][16];
  __shared__ float Ws[4][64];
  const int i0 = blockIdx.x * 64;
  const int h  = blockIdx.y;
  const int tid = threadIdx.x;
  const int il = tid & 63, rr = tid >> 6;
  for (int t = tid; t < 64*16; t += 256)
    Us[t >> 4][t & 15] = U[(size_t)(h*DK + (t >> 4))*RK + (t & 15)];
  float acc[4] = {};
  for (int d0 = 0; d0 < DK; d0 += 4) {
    __syncthreads();
    Ws[rr][il] = W[(size_t)(h*DK + d0 + rr)*DM + i0 + il];
    __syncthreads();
#pragma unroll
    for (int dd = 0; dd < 4; ++dd) {
      const float w = Ws[dd][il];
#pragma unroll
      for (int j = 0; j < 4; ++j)
        acc[j] += w * Us[d0 + dd][rr*4 + j];
    }
  }
#pragma unroll
  for (int j = 0; j < 4; ++j)
    At[(size_t)(h*RK + rr*4 + j)*DM + i0 + il] = f2b(acc[j]);
}

// both bias projections in one launch: 512 threads
__global__ void bias2(const float* __restrict__ bq, const float* __restrict__ bk,
                      const float* __restrict__ Uq, const float* __restrict__ Uk,
                      float* __restrict__ bpq, float* __restrict__ bpk) {
  const int t = threadIdx.x;
  const float* b = (t < 256) ? bq : bk;
  const float* U = (t < 256) ? Uq : Uk;
  float* bp = (t < 256) ? bpq : bpk;
  const int hr = t & 255, h = hr >> 4, r = hr & 15;
  float acc = 0.f;
  for (int d = 0; d < DK; ++d)
    acc += b[h*DK + d] * U[(size_t)(h*DK + d)*RK + r];
  bp[hr] = acc;
}

// ---------------------------------------------------------------------------
// Vsum[b][h][d] = sum_l Vt[b][h*64+d][l]   (exact fp32 from bf16 Vt)
// grid (NH, BB), 256 threads: d = tid>>2, 4 threads/d over 512-chunks
// ---------------------------------------------------------------------------
__global__ __launch_bounds__(256) void vsum_k(
    const unsigned short* __restrict__ Vt, float* __restrict__ Vsum) {
  const int h = blockIdx.x, b = blockIdx.y;
  const int d = threadIdx.x >> 2, part = threadIdx.x & 3;
  const unsigned short* row = Vt + ((size_t)b*DM + h*DK + d)*LL + part*512;
  float s = 0.f;
  for (int i = 0; i < 512; i += 8) {
    const s8v v = *(const s8v*)&row[i];
#pragma unroll
    for (int j = 0; j < 8; ++j) s += b2f((unsigned short)v[j]);
  }
  s += __shfl_xor(s, 1);
  s += __shfl_xor(s, 2);
  if (part == 0) Vsum[((size_t)b*NH + h)*DK + d] = s;
}

// ---------------------------------------------------------------------------
// bf16 MFMA GEMM, 64x128 tile (4 waves, each 64m x 32n), BK=32.
// C[t][n] = sum_k A[t][k]*B[n][k] + bias[n].  blockIdx.z selects operand set.
// MODE: 0 fp32 row-major; 1 bf16 row-major; 2 bf16 transposed Vt[b][n][l].
// AF32: A operand is fp32 in global, converted during staging.
// ---------------------------------------------------------------------------
template<int N_, int MODE, int AF32>
__global__ __launch_bounds__(256) void gemm64(
    const void* __restrict__ A0, const void* __restrict__ A1,
    const unsigned short* __restrict__ B0, const unsigned short* __restrict__ B1,
    const float* __restrict__ bi0, const float* __restrict__ bi1,
    void* __restrict__ C0, void* __restrict__ C1) {
  const void* Agv = blockIdx.z ? A1 : A0;
  const unsigned short* Bg = blockIdx.z ? B1 : B0;
  const float* bias = blockIdx.z ? bi1 : bi0;
  void* Cgv = blockIdx.z ? C1 : C0;
  __shared__ unsigned short Xs[64*40];
  __shared__ unsigned short Bs[128*40];
  const int t0 = blockIdx.x * 64, n0 = blockIdx.y * 128;
  const int tid = threadIdx.x, wave = tid >> 6, lane = tid & 63;
  const int quad = lane >> 4, l15 = lane & 15;
  const int nh = wave * 32;

  const f4 z = {0.f, 0.f, 0.f, 0.f};
  f4 acc[4][2];
#pragma unroll
  for (int a = 0; a < 4; ++a) { acc[a][0] = z; acc[a][1] = z; }

  for (int k0 = 0; k0 < DM; k0 += 32) {
    __syncthreads();
    {  // A tile: 64 rows x 32 halfs, 4 threads/row
      const int ar = tid >> 2, ap = tid & 3;
      if (AF32) {
        const float* Af = (const float*)Agv;
        const float4 x0 = *(const float4*)&Af[(size_t)(t0 + ar)*DM + k0 + ap*8];
        const float4 x1 = *(const float4*)&Af[(size_t)(t0 + ar)*DM + k0 + ap*8 + 4];
        s8v v;
        v[0]=(short)f2b(x0.x); v[1]=(short)f2b(x0.y);
        v[2]=(short)f2b(x0.z); v[3]=(short)f2b(x0.w);
        v[4]=(short)f2b(x1.x); v[5]=(short)f2b(x1.y);
        v[6]=(short)f2b(x1.z); v[7]=(short)f2b(x1.w);
        *(s8v*)&Xs[ar*40 + ap*8] = v;
      } else {
        *(s8v*)&Xs[ar*40 + ap*8] =
            *(const s8v*)&((const unsigned short*)Agv)[(size_t)(t0 + ar)*DM + k0 + ap*8];
      }
      // B tile: 128 rows x 32 halfs, 2 threads/row
      const int br = tid >> 1, bp = tid & 1;
      *(s8v*)&Bs[br*40 + bp*16] =
          *(const s8v*)&Bg[(size_t)(n0 + br)*DM + k0 + bp*16];
      *(s8v*)&Bs[br*40 + bp*16 + 8] =
          *(const s8v*)&Bg[(size_t)(n0 + br)*DM + k0 + bp*16 + 8];
    }
    __syncthreads();

    s8v af[4], bf[2];
#pragma unroll
    for (int ms = 0; ms < 4; ++ms)
      af[ms] = *(const s8v*)&Xs[(ms*16 + l15)*40 + quad*8];
#pragma unroll
    for (int ns = 0; ns < 2; ++ns)
      bf[ns] = *(const s8v*)&Bs[(nh + ns*16 + l15)*40 + quad*8];
#pragma unroll
    for (int ms = 0; ms < 4; ++ms)
#pragma unroll
      for (int ns = 0; ns < 2; ++ns)
        acc[ms][ns] = __builtin_amdgcn_mfma_f32_16x16x32_bf16(
            af[ms], bf[ns], acc[ms][ns], 0, 0, 0);
  }

#pragma unroll
  for (int ms = 0; ms < 4; ++ms) {
    const int tb = t0 + ms*16 + quad*4;
#pragma unroll
    for (int ns = 0; ns < 2; ++ns) {
      const int o = n0 + nh + ns*16 + l15;
      const float bv = bias[o];
      f4 a = acc[ms][ns];
      if (MODE == 0) {
        float* C = (float*)Cgv;
#pragma unroll
        for (int rg = 0; rg < 4; ++rg)
          C[(size_t)(tb + rg)*N_ + o] = a[rg] + bv;
      } else if (MODE == 1) {
        unsigned short* C = (unsigned short*)Cgv;
#pragma unroll
        for (int rg = 0; rg < 4; ++rg)
          C[(size_t)(tb + rg)*N_ + o] = f2b(a[rg] + bv);
      } else {
        unsigned short* C = (unsigned short*)Cgv;   // Vt[b][o][l]
        const int bb = tb >> 11, l = tb & 2047;
        ushort4 pk;
        pk.x = f2b(a[0] + bv); pk.y = f2b(a[1] + bv);
        pk.z = f2b(a[2] + bv); pk.w = f2b(a[3] + bv);
        *(ushort4*)&C[((size_t)bb*DM + o)*LL + l] = pk;
      }
    }
  }
}

// ---------------------------------------------------------------------------
// Attention v4: 32x32x16 MFMA, rank 16, q-tile 128/block (wave = 32 q rows).
// E' = e*m - 1 stored bf16; ctx = (Vsum + sum E'v) / den, ctx fp32.
// S^T = mfma(Kfrag, Qfrag): D col=lane&31=q, row=(reg&3)+8*(reg>>2)+4*hi=k.
// ---------------------------------------------------------------------------
__global__ __launch_bounds__(256) void attention_v4(
    const unsigned short* __restrict__ Qp, const unsigned short* __restrict__ Kp,
    const unsigned short* __restrict__ Vt, const float* __restrict__ Vsum,
    const unsigned char* __restrict__ msk, float* __restrict__ ctx) {
  __shared__ unsigned short Ks[64*24];     // [kpos][16 r], stride 24
  __shared__ unsigned short Vs[64*72];     // [d][64 kpos], stride 72
  __shared__ unsigned short Es[4][32*48];  // per-wave [32 q][64 k], stride 48
  __shared__ float denW[4][32];
  const int q0 = blockIdx.x * 128, h = blockIdx.y, b = blockIdx.z;
  const int tid = threadIdx.x, w = tid >> 6, lane = tid & 63;
  const int l31 = lane & 31, hi = lane >> 5;
  unsigned short* __restrict__ Ew = Es[w];

  // Q B-frag: n=l31 (q within wave's 32), k-dim = hi*8 + j  (rank 16)
  const s8v qfrag = *(const s8v*)&Qp[
      (size_t)(b*LL + q0 + w*32 + l31)*HRK + h*RK + hi*8];

  f16v acc0, acc1, z16;
#pragma unroll
  for (int i = 0; i < 16; ++i) { acc0[i] = 0.f; acc1[i] = 0.f; z16[i] = 0.f; }
  float den = 0.f;

  for (int k0 = 0; k0 < LL; k0 += 64) {
    __syncthreads();
    if (tid < 128) {   // stage K: 64 rows x 16 halfs
      const int row = tid >> 1, part = tid & 1;
      *(s8v*)&Ks[row*24 + part*8] =
          *(const s8v*)&Kp[(size_t)(b*LL + k0 + row)*HRK + h*RK + part*8];
    }
    {                  // stage V^T: 64 d-rows x 64 halfs
      const int d = tid >> 2, p = tid & 3;
      const size_t gv = ((size_t)b*DM + h*DK + d)*LL + k0 + p*16;
      *(s8v*)&Vs[d*72 + p*16]     = *(const s8v*)&Vt[gv];
      *(s8v*)&Vs[d*72 + p*16 + 8] = *(const s8v*)&Vt[gv + 8];
    }
    const unsigned long long mb =
        __ballot(msk[(size_t)b*LL + k0 + lane] != 0);   // bit i = mask[k0+i]
    __syncthreads();

    // ---- S^T phase: 2 MFMA cover 64 k x 32 q; write E' = e*m - 1 ----
#pragma unroll
    for (int nt = 0; nt < 2; ++nt) {
      const s8v kf = *(const s8v*)&Ks[(nt*32 + l31)*24 + hi*8];
      f16v s = __builtin_amdgcn_mfma_f32_32x32x16_bf16(kf, qfrag, z16, 0, 0, 0);
#pragma unroll
      for (int r = 0; r < 4; ++r) {
        ushort4 pk;
#pragma unroll
        for (int j = 0; j < 4; ++j) {
          const int kloc = nt*32 + j + 8*r + 4*hi;   // reg = r*4+j
          float em = __expf(s[r*4 + j] * 0.25f);
          if ((mb >> kloc) & 1ull) em = 0.f;
          den += em;
          ((unsigned short*)&pk)[j] = f2b(em - 1.f);
        }
        *(ushort4*)&Ew[l31*48 + nt*32 + r*8 + 4*hi] = pk;
      }
    }
    // ---- PV phase: 4 K=16 chunks x 2 d-halves ----
#pragma unroll
    for (int kc = 0; kc < 4; ++kc) {
      const s8v ef  = *(const s8v*)&Ew[l31*48 + kc*16 + hi*8];
      const s8v vf0 = *(const s8v*)&Vs[l31*72 + kc*16 + hi*8];
      const s8v vf1 = *(const s8v*)&Vs[(32 + l31)*72 + kc*16 + hi*8];
      acc0 = __builtin_amdgcn_mfma_f32_32x32x16_bf16(ef, vf0, acc0, 0, 0, 0);
      acc1 = __builtin_amdgcn_mfma_f32_32x32x16_bf16(ef, vf1, acc1, 0, 0, 0);
    }
  }

  // den: lane holds half the k-sum for q=l31; combine hi halves
  den += __shfl_xor(den, 32);
  if (hi == 0) denW[w][l31] = 1.f / fmaxf(den, 1e-30f);

  const float vs0 = Vsum[((size_t)b*NH + h)*DK + l31];
  const float vs1 = Vsum[((size_t)b*NH + h)*DK + 32 + l31];

#pragma unroll
  for (int rg = 0; rg < 16; ++rg) {
    const int qr = (rg & 3) + 8*(rg >> 2) + 4*hi;     // PV D row = q
    const float inv = denW[w][qr];
    const size_t row = (size_t)(b*LL + q0 + w*32 + qr)*DM + h*DK;
    ctx[row + l31]      = (vs0 + acc0[rg]) * inv;
    ctx[row + 32 + l31] = (vs1 + acc1[rg]) * inv;
  }
}

// ---------------------------------------------------------------------------
extern "C" void kernel_launch(void* const* d_in, const int* in_sizes, int n_in,
                              void* d_out, int out_size, void* d_ws, size_t ws_size,
                              hipStream_t stream) {
  (void)in_sizes; (void)n_in; (void)out_size; (void)ws_size;
  const float* x_q   = (const float*)d_in[0];
  const float* x_kv  = (const float*)d_in[1];
  const float* Wq    = (const float*)d_in[2];
  const float* bq    = (const float*)d_in[3];
  const float* Wk    = (const float*)d_in[4];
  const float* bk    = (const float*)d_in[5];
  const float* Wv    = (const float*)d_in[6];
  const float* bv    = (const float*)d_in[7];
  const float* Wo    = (const float*)d_in[8];
  const float* bo    = (const float*)d_in[9];
  const float* U_bil = (const float*)d_in[10];
  const float* V_bil = (const float*)d_in[11];
  const unsigned char* pmask = (const unsigned char*)d_in[12];  // all-False
  float* out = (float*)d_out;

  // Workspace layout, 34.6 MB (< 38 MB proven in r7).
  // ctx (fp32, 16 MB) aliases xq_b+xkv_b, both dead after the Vt GEMM.
  char* w = (char*)d_ws;
  unsigned short* xq_b  = (unsigned short*)(w);             //  8 MB
  unsigned short* xkv_b = (unsigned short*)(w +  8388608);  //  8 MB
  unsigned short* Wv_b  = (unsigned short*)(w + 16777216);  //  2 MB
  unsigned short* Wo_b  = (unsigned short*)(w + 18874368);  //  2 MB
  unsigned short* Atq   = (unsigned short*)(w + 20971520);  //  0.5 MB
  unsigned short* Atk   = (unsigned short*)(w + 21495808);  //  0.5 MB
  float*          bpq   = (float*)(w + 22020096);           //  1 KB
  float*          bpk   = (float*)(w + 22021120);           //  1 KB
  unsigned short* Qp    = (unsigned short*)(w + 22022144);  //  2 MB
  unsigned short* Kp    = (unsigned short*)(w + 24119296);  //  2 MB
  unsigned short* Vt    = (unsigned short*)(w + 26216448);  //  8 MB
  float*          Vsum  = (float*)(w + 34605056);           //  8 KB
  float*          ctx   = (float*)w;                        //  16 MB aliased

  cast_all<<<dim3(1024, 4), 256, 0, stream>>>(
      x_q, xq_b, TT*DM/4, x_kv, xkv_b, TT*DM/4,
      Wv, Wv_b, DM*DM/4,  Wo, Wo_b, DM*DM/4);
  fuse_w<<<dim3(DM/64, NH, 2), 256, 0, stream>>>(Wq, Wk, U_bil, V_bil, Atq, Atk);
  bias2<<<1, 512, 0, stream>>>(bq, bk, U_bil, V_bil, bpq, bpk);
  // Qp/Kp: [4096][256] bf16, q (z=0) and k (z=1) in one launch
  gemm64<HRK, 1, 0><<<dim3(64, 2, 2), 256, 0, stream>>>(
      xq_b, xkv_b, Atq, Atk, bpq, bpk, Qp, Kp);
  // V: transposed bf16 store Vt[b][o][l]
  gemm64<DM, 2, 0><<<dim3(64, 8, 1), 256, 0, stream>>>(
      xkv_b, xkv_b, Wv_b, Wv_b, bv, bv, Vt, Vt);
  vsum_k<<<dim3(NH, BB), 256, 0, stream>>>(Vt, Vsum);
  attention_v4<<<dim3(LL/128, NH, BB), 256, 0, stream>>>(
      Qp, Kp, Vt, Vsum, pmask, ctx);
  // out = ctx(fp32) @ Wo^T + bo, fp32 store
  gemm64<DM, 0, 1><<<dim3(64, 8, 1), 256, 0, stream>>>(
      ctx, ctx, Wo_b, Wo_b, bo, bo, out, out);
}